// Round 3
// baseline (14442.485 us; speedup 1.0000x reference)
//
#include <hip/hip_runtime.h>

// LSTM B=64, T=2048, D=256, H=512 — split-bf16 (hi+lo) compute, FP32 output.
// 64 WGs = 4 batch-groups (M=16) x 16 hidden-slices (32 hu each).
// Persistent kernel over 2048 steps; per-group epoch-counter sync per step.
// All GEMMs: A*B ~= Ah*Bh + Al*Bh + Ah*Bl (fp32 accum) -> ~fp32-accurate.
//
// R3: critical-path surgery.
//  - x(t+1) prefetched into VGPRs during step t (HBM latency hidden)
//  - group->XCD swizzle (g=bid&3, s=bid>>2): group's 16 WGs on 2 XCDs -> x
//    shared via L2 (FETCH should drop ~4x)
//  - h exchange as ONE u64 sc1 store per thread (hi|lo packed) and 16
//    contiguous u64 loads per consumer thread (was 2x16 scattered u32)
//  - Phase D (y GEMM) + y store moved AFTER flag publish (off the period)

typedef __attribute__((ext_vector_type(8))) short bf16x8;
typedef __attribute__((ext_vector_type(4))) float f32x4;

#define T_STEPS 2048
#define DIMS 256
#define HID 512

#define NPACK_U  1048576
#define NPACK_WX 524288
#define NPACK_WY 131072

// workspace layout (bytes)
#define OFF_UHI   0u          // 2,097,152
#define OFF_ULO   2097152u    // 2,097,152
#define OFF_WXHI  4194304u    // 1,048,576
#define OFF_WXLO  5242880u    // 1,048,576
#define OFF_WYHI  6291456u    //   262,144
#define OFF_WYLO  6553600u    //   262,144
#define OFF_HBUF  6815744u    //   262,144 (2 parity x 64 rows x 256 u64)
#define OFF_FLAGS 7077888u    //   64 u32 (only [0..3] used as epoch counters)

__device__ __forceinline__ unsigned short f2bf(float f) {
    unsigned u = __float_as_uint(f);
    return (unsigned short)((u + 0x7fffu + ((u >> 16) & 1u)) >> 16);
}
__device__ __forceinline__ float bf2f(unsigned short h) {
    return __uint_as_float((unsigned)h << 16);
}
__device__ __forceinline__ void split2(float f, unsigned short& hi, unsigned short& lo) {
    hi = f2bf(f);
    lo = f2bf(f - bf2f(hi));
}
__device__ __forceinline__ float sigf(float x) { return 1.0f / (1.0f + __expf(-x)); }
__device__ __forceinline__ float tanhfast(float x) { return 2.0f * sigf(2.0f * x) - 1.0f; }

// ---------------- prep: pack weights (hi+lo) into MFMA B-frag layout --------
// B-frag (16x16x32 bf16): lane l holds B[k = (l>>4)*8 + j][n = l&15], j=0..7.
__global__ void lstm_prep(const float* __restrict__ Uj, const float* __restrict__ Ui,
                          const float* __restrict__ Uf, const float* __restrict__ Uo,
                          const float* __restrict__ Wj, const float* __restrict__ Wi,
                          const float* __restrict__ Wf, const float* __restrict__ Wo,
                          const float* __restrict__ Wy,
                          unsigned short* __restrict__ Uph, unsigned short* __restrict__ Upl,
                          unsigned short* __restrict__ Wxh, unsigned short* __restrict__ Wxl,
                          unsigned short* __restrict__ Wyh, unsigned short* __restrict__ Wyl,
                          unsigned* __restrict__ flags) {
    int idx = blockIdx.x * 256 + threadIdx.x;
    if (idx < NPACK_U) {
        int j = idx & 7, l = (idx >> 3) & 63, ks = (idx >> 9) & 15, nt = (idx >> 13) & 7, s = (idx >> 16) & 15;
        int gate = nt >> 1;
        int hu = s * 32 + (nt & 1) * 16 + (l & 15);
        int k = ks * 32 + ((l >> 4) << 3) + j;
        const float* U = (gate == 0) ? Uj : (gate == 1) ? Ui : (gate == 2) ? Uf : Uo;
        unsigned short hi, lo; split2(U[k * HID + hu], hi, lo);
        Uph[idx] = hi; Upl[idx] = lo;
    } else if (idx < NPACK_U + NPACK_WX) {
        int i2 = idx - NPACK_U;
        int j = i2 & 7, l = (i2 >> 3) & 63, ks = (i2 >> 9) & 7, nt = (i2 >> 12) & 7, s = (i2 >> 15) & 15;
        int gate = nt >> 1;
        int hu = s * 32 + (nt & 1) * 16 + (l & 15);
        int k = ks * 32 + ((l >> 4) << 3) + j;
        const float* W = (gate == 0) ? Wj : (gate == 1) ? Wi : (gate == 2) ? Wf : Wo;
        unsigned short hi, lo; split2(W[k * HID + hu], hi, lo);
        Wxh[i2] = hi; Wxl[i2] = lo;
    } else if (idx < NPACK_U + NPACK_WX + NPACK_WY) {
        int i3 = idx - NPACK_U - NPACK_WX;
        int j = i3 & 7, l = (i3 >> 3) & 63, ks = (i3 >> 9) & 15, s = (i3 >> 13) & 15;
        int k = ks * 32 + ((l >> 4) << 3) + j;
        int col = s * 16 + (l & 15);
        unsigned short hi, lo; split2(Wy[k * DIMS + col], hi, lo);
        Wyh[i3] = hi; Wyl[i3] = lo;
    } else if (idx < NPACK_U + NPACK_WX + NPACK_WY + 64) {
        flags[idx - (NPACK_U + NPACK_WX + NPACK_WY)] = 0u;
    }
}

// ---------------- main persistent scan kernel -------------------------------
__global__ __launch_bounds__(256, 1) void lstm_scan(
    const float* __restrict__ x, const float* __restrict__ h0, const float* __restrict__ c0,
    const float* __restrict__ bj_g, const float* __restrict__ bi_g,
    const float* __restrict__ bf_g, const float* __restrict__ bo_g,
    const float* __restrict__ by_g,
    const unsigned short* __restrict__ Uph, const unsigned short* __restrict__ Upl,
    const unsigned short* __restrict__ Wxph, const unsigned short* __restrict__ Wxpl,
    const unsigned short* __restrict__ Wyph, const unsigned short* __restrict__ Wypl,
    unsigned long long* __restrict__ hbuf64, unsigned* __restrict__ flags,
    float* __restrict__ out)
{
    __shared__ unsigned short xsh[16][264];  // x_t hi (pitch 264)
    __shared__ unsigned short xsl[16][264];  // x_t lo
    __shared__ unsigned short hsh[16][520];  // h_{t-1} hi (pitch 520)
    __shared__ unsigned short hsl[16][520];  // h_{t-1} lo
    __shared__ float pre[8][16][17];         // gate pre-activations
    __shared__ float yp[4][16][17];          // y partials (per-wave K-split)
    __shared__ float cbuf[16][32];           // cell state (fp32, persistent)

    const int tid = threadIdx.x;
    const int wv = tid >> 6;
    const int l = tid & 63;
    const int quad = l >> 4;
    const int lm = l & 15;
    // group->XCD swizzle: bid = s*4 + g => group g occupies XCDs {g, g+4};
    // its 16 lock-stepped WGs share x lines in those 2 L2s.
    const int g = blockIdx.x & 3;    // batch group
    const int s = blockIdx.x >> 2;   // hidden slice

    // --- persistent B fragments in VGPRs (hi + lo) ---
    bf16x8 bUh[2][16], bUl[2][16], bWxh[2][8], bWxl[2][8], bWyh[4], bWyl[4];
    {
        const bf16x8* UH = reinterpret_cast<const bf16x8*>(Uph);
        const bf16x8* UL = reinterpret_cast<const bf16x8*>(Upl);
        const bf16x8* WH = reinterpret_cast<const bf16x8*>(Wxph);
        const bf16x8* WL = reinterpret_cast<const bf16x8*>(Wxpl);
        const bf16x8* YH = reinterpret_cast<const bf16x8*>(Wyph);
        const bf16x8* YL = reinterpret_cast<const bf16x8*>(Wypl);
        #pragma unroll
        for (int i = 0; i < 2; ++i) {
            int nt = 2 * wv + i;
            #pragma unroll
            for (int ks = 0; ks < 16; ++ks) {
                bUh[i][ks] = UH[((s * 8 + nt) * 16 + ks) * 64 + l];
                bUl[i][ks] = UL[((s * 8 + nt) * 16 + ks) * 64 + l];
            }
            #pragma unroll
            for (int ks = 0; ks < 8; ++ks) {
                bWxh[i][ks] = WH[((s * 8 + nt) * 8 + ks) * 64 + l];
                bWxl[i][ks] = WL[((s * 8 + nt) * 8 + ks) * 64 + l];
            }
        }
        #pragma unroll
        for (int q = 0; q < 4; ++q) {
            bWyh[q] = YH[(s * 16 + wv * 4 + q) * 64 + l];
            bWyl[q] = YL[(s * 16 + wv * 4 + q) * 64 + l];
        }
    }

    const int rr = tid >> 4;            // owned batch row
    const int uu = (tid & 15) * 2;      // owned local hidden units uu, uu+1
    cbuf[rr][uu]     = c0[(size_t)(g * 16 + rr) * HID + s * 32 + uu];
    cbuf[rr][uu + 1] = c0[(size_t)(g * 16 + rr) * HID + s * 32 + uu + 1];
    float bj0 = bj_g[s * 32 + uu], bj1 = bj_g[s * 32 + uu + 1];
    float bi0 = bi_g[s * 32 + uu], bi1 = bi_g[s * 32 + uu + 1];
    float bf0 = bf_g[s * 32 + uu], bf1 = bf_g[s * 32 + uu + 1];
    float bo0 = bo_g[s * 32 + uu], bo1 = bo_g[s * 32 + uu + 1];
    const float by = by_g[s * 16 + (tid & 15)];

    const int rS = tid >> 4;            // staging row
    const int cS16 = (tid & 15) * 16;   // x staging col (bf16 units)
    const int cS32 = (tid & 15) * 32;   // h staging col (bf16 units)
    long long budget = 1ll << 24;

    // --- prefetch x(0) into registers ---
    float4 xr[4];
    {
        const float4* xv = reinterpret_cast<const float4*>(
            x + (size_t)(g * 16 + rS) * (T_STEPS * DIMS) + cS16);
        xr[0] = xv[0]; xr[1] = xv[1]; xr[2] = xv[2]; xr[3] = xv[3];
    }

    __syncthreads();

    for (int t = 0; t < T_STEPS; ++t) {
        // ---- Phase A: stage x_t from prefetch regs; issue prefetch x(t+1) ----
        {
            float4 f0 = xr[0], f1 = xr[1], f2 = xr[2], f3 = xr[3];
            if (t + 1 < T_STEPS) {
                const float4* xv = reinterpret_cast<const float4*>(
                    x + (size_t)(g * 16 + rS) * (T_STEPS * DIMS) + (size_t)(t + 1) * DIMS + cS16);
                xr[0] = xv[0]; xr[1] = xv[1]; xr[2] = xv[2]; xr[3] = xv[3];
            }
            uint4* xdh = reinterpret_cast<uint4*>(&xsh[rS][cS16]);
            uint4* xdl = reinterpret_cast<uint4*>(&xsl[rS][cS16]);
            unsigned short h0_, l0_, h1_, l1_, h2_, l2_, h3_, l3_;
            unsigned short h4_, l4_, h5_, l5_, h6_, l6_, h7_, l7_;
            uint4 uh, ul;
            split2(f0.x, h0_, l0_); split2(f0.y, h1_, l1_);
            split2(f0.z, h2_, l2_); split2(f0.w, h3_, l3_);
            split2(f1.x, h4_, l4_); split2(f1.y, h5_, l5_);
            split2(f1.z, h6_, l6_); split2(f1.w, h7_, l7_);
            uh.x = (unsigned)h0_ | ((unsigned)h1_ << 16);
            uh.y = (unsigned)h2_ | ((unsigned)h3_ << 16);
            uh.z = (unsigned)h4_ | ((unsigned)h5_ << 16);
            uh.w = (unsigned)h6_ | ((unsigned)h7_ << 16);
            ul.x = (unsigned)l0_ | ((unsigned)l1_ << 16);
            ul.y = (unsigned)l2_ | ((unsigned)l3_ << 16);
            ul.z = (unsigned)l4_ | ((unsigned)l5_ << 16);
            ul.w = (unsigned)l6_ | ((unsigned)l7_ << 16);
            xdh[0] = uh; xdl[0] = ul;
            split2(f2.x, h0_, l0_); split2(f2.y, h1_, l1_);
            split2(f2.z, h2_, l2_); split2(f2.w, h3_, l3_);
            split2(f3.x, h4_, l4_); split2(f3.y, h5_, l5_);
            split2(f3.z, h6_, l6_); split2(f3.w, h7_, l7_);
            uh.x = (unsigned)h0_ | ((unsigned)h1_ << 16);
            uh.y = (unsigned)h2_ | ((unsigned)h3_ << 16);
            uh.z = (unsigned)h4_ | ((unsigned)h5_ << 16);
            uh.w = (unsigned)h6_ | ((unsigned)h7_ << 16);
            ul.x = (unsigned)l0_ | ((unsigned)l1_ << 16);
            ul.y = (unsigned)l2_ | ((unsigned)l3_ << 16);
            ul.z = (unsigned)l4_ | ((unsigned)l5_ << 16);
            ul.w = (unsigned)l6_ | ((unsigned)l7_ << 16);
            xdh[1] = uh; xdl[1] = ul;
        }
        __syncthreads();
        f32x4 acc0 = {0.f, 0.f, 0.f, 0.f}, acc1 = {0.f, 0.f, 0.f, 0.f};
        #pragma unroll
        for (int ks = 0; ks < 8; ++ks) {
            bf16x8 ah = *reinterpret_cast<const bf16x8*>(&xsh[lm][ks * 32 + quad * 8]);
            bf16x8 al = *reinterpret_cast<const bf16x8*>(&xsl[lm][ks * 32 + quad * 8]);
            acc0 = __builtin_amdgcn_mfma_f32_16x16x32_bf16(ah, bWxh[0][ks], acc0, 0, 0, 0);
            acc0 = __builtin_amdgcn_mfma_f32_16x16x32_bf16(al, bWxh[0][ks], acc0, 0, 0, 0);
            acc0 = __builtin_amdgcn_mfma_f32_16x16x32_bf16(ah, bWxl[0][ks], acc0, 0, 0, 0);
            acc1 = __builtin_amdgcn_mfma_f32_16x16x32_bf16(ah, bWxh[1][ks], acc1, 0, 0, 0);
            acc1 = __builtin_amdgcn_mfma_f32_16x16x32_bf16(al, bWxh[1][ks], acc1, 0, 0, 0);
            acc1 = __builtin_amdgcn_mfma_f32_16x16x32_bf16(ah, bWxl[1][ks], acc1, 0, 0, 0);
        }

        // ---- Phase B: wait for peers' h[t-1] (epoch counter), load + stage ----
        if (t > 0) {
            const unsigned target = 16u * (unsigned)t;
            while (budget > 0) {
                unsigned v = __hip_atomic_load(&flags[g], __ATOMIC_RELAXED, __HIP_MEMORY_SCOPE_AGENT);
                if (v >= target) break;
                --budget;
            }
            asm volatile("" ::: "memory");   // data travels sc1, same path as poll
            const unsigned long long* src = hbuf64 + (unsigned)(((t - 1) & 1) * 16384)
                                            + (unsigned)(g * 16 + rS) * 256 + (unsigned)(tid & 15) * 16;
            unsigned long long v64[16];
            #pragma unroll
            for (int k = 0; k < 16; ++k)
                v64[k] = __hip_atomic_load(&src[k], __ATOMIC_RELAXED, __HIP_MEMORY_SCOPE_AGENT);
            unsigned long long* dh = reinterpret_cast<unsigned long long*>(&hsh[rS][cS32]);
            unsigned long long* dl = reinterpret_cast<unsigned long long*>(&hsl[rS][cS32]);
            #pragma unroll
            for (int m = 0; m < 8; ++m) {
                dh[m] = (unsigned long long)(unsigned)v64[2 * m]
                        | ((unsigned long long)(unsigned)v64[2 * m + 1] << 32);
                dl[m] = (unsigned long long)(unsigned)(v64[2 * m] >> 32)
                        | ((unsigned long long)(unsigned)(v64[2 * m + 1] >> 32) << 32);
            }
        } else {
            const float4* hv = reinterpret_cast<const float4*>(
                h0 + (size_t)(g * 16 + rS) * HID + cS32);
            unsigned* hdh = reinterpret_cast<unsigned*>(&hsh[rS][cS32]);
            unsigned* hdl = reinterpret_cast<unsigned*>(&hsl[rS][cS32]);
            #pragma unroll
            for (int k = 0; k < 8; ++k) {
                float4 f = hv[k];
                unsigned short a0, b0, a1, b1, a2, b2, a3, b3;
                split2(f.x, a0, b0); split2(f.y, a1, b1);
                split2(f.z, a2, b2); split2(f.w, a3, b3);
                hdh[2 * k]     = (unsigned)a0 | ((unsigned)a1 << 16);
                hdh[2 * k + 1] = (unsigned)a2 | ((unsigned)a3 << 16);
                hdl[2 * k]     = (unsigned)b0 | ((unsigned)b1 << 16);
                hdl[2 * k + 1] = (unsigned)b2 | ((unsigned)b3 << 16);
            }
        }
        __syncthreads();

        // ---- Phase C: recurrent GEMM h[t-1] @ U_slice (3-pass split) ----
        #pragma unroll
        for (int ks = 0; ks < 16; ++ks) {
            bf16x8 ah = *reinterpret_cast<const bf16x8*>(&hsh[lm][ks * 32 + quad * 8]);
            bf16x8 al = *reinterpret_cast<const bf16x8*>(&hsl[lm][ks * 32 + quad * 8]);
            acc0 = __builtin_amdgcn_mfma_f32_16x16x32_bf16(ah, bUh[0][ks], acc0, 0, 0, 0);
            acc0 = __builtin_amdgcn_mfma_f32_16x16x32_bf16(al, bUh[0][ks], acc0, 0, 0, 0);
            acc0 = __builtin_amdgcn_mfma_f32_16x16x32_bf16(ah, bUl[0][ks], acc0, 0, 0, 0);
            acc1 = __builtin_amdgcn_mfma_f32_16x16x32_bf16(ah, bUh[1][ks], acc1, 0, 0, 0);
            acc1 = __builtin_amdgcn_mfma_f32_16x16x32_bf16(al, bUh[1][ks], acc1, 0, 0, 0);
            acc1 = __builtin_amdgcn_mfma_f32_16x16x32_bf16(ah, bUl[1][ks], acc1, 0, 0, 0);
        }
        #pragma unroll
        for (int r = 0; r < 4; ++r) {
            pre[2 * wv][quad * 4 + r][lm]     = acc0[r];
            pre[2 * wv + 1][quad * 4 + r][lm] = acc1[r];
        }
        __syncthreads();

        // ---- gates + cell update; publish h[t] (single u64 per thread) ----
        {
            unsigned short hh[2], hl[2];
            #pragma unroll
            for (int d = 0; d < 2; ++d) {
                int u = uu + d;
                int nt = u >> 4, cc = u & 15;
                float pj = pre[nt][rr][cc]     + (d ? bj1 : bj0);
                float pi = pre[2 + nt][rr][cc] + (d ? bi1 : bi0);
                float pf = pre[4 + nt][rr][cc] + (d ? bf1 : bf0);
                float po = pre[6 + nt][rr][cc] + (d ? bo1 : bo0);
                float jj = sigf(pj), ii = sigf(pi), ff = tanhfast(pf), oo = sigf(po);
                float cn = ff * cbuf[rr][u] + ii * jj;
                cbuf[rr][u] = cn;
                float hn = oo * tanhfast(cn);
                split2(hn, hh[d], hl[d]);
            }
            unsigned pkh = (unsigned)hh[0] | ((unsigned)hh[1] << 16);
            unsigned pkl = (unsigned)hl[0] | ((unsigned)hl[1] << 16);
            unsigned long long hv64 = (unsigned long long)pkh | ((unsigned long long)pkl << 32);
            unsigned wbase = (unsigned)((t & 1) * 16384) + (unsigned)(g * 16 + rr) * 256
                             + (unsigned)s * 16 + (unsigned)(tid & 15);
            __hip_atomic_store(hbuf64 + wbase, hv64, __ATOMIC_RELAXED, __HIP_MEMORY_SCOPE_AGENT);
        }
        // sc1 stores are IF$-bound; vmcnt(0) == "data visible at coherence point"
        asm volatile("s_waitcnt vmcnt(0)" ::: "memory");
        __syncthreads();
        if (tid == 0)
            (void)__hip_atomic_fetch_add(&flags[g], 1u, __ATOMIC_RELAXED, __HIP_MEMORY_SCOPE_AGENT);

        // ---- Phase D: y[t-1] = h[t-1] @ Wy_slice (off the inter-WG path) ----
        if (t > 0) {
            f32x4 yacc = {0.f, 0.f, 0.f, 0.f};
            #pragma unroll
            for (int q = 0; q < 4; ++q) {
                bf16x8 ah = *reinterpret_cast<const bf16x8*>(&hsh[lm][(wv * 4 + q) * 32 + quad * 8]);
                bf16x8 al = *reinterpret_cast<const bf16x8*>(&hsl[lm][(wv * 4 + q) * 32 + quad * 8]);
                yacc = __builtin_amdgcn_mfma_f32_16x16x32_bf16(ah, bWyh[q], yacc, 0, 0, 0);
                yacc = __builtin_amdgcn_mfma_f32_16x16x32_bf16(al, bWyh[q], yacc, 0, 0, 0);
                yacc = __builtin_amdgcn_mfma_f32_16x16x32_bf16(ah, bWyl[q], yacc, 0, 0, 0);
            }
            #pragma unroll
            for (int r = 0; r < 4; ++r) yp[wv][quad * 4 + r][lm] = yacc[r];
            __syncthreads();
            int row = tid >> 4, col = tid & 15;
            float yv = yp[0][row][col] + yp[1][row][col] + yp[2][row][col] + yp[3][row][col] + by;
            out[(size_t)(g * 16 + row) * (T_STEPS * DIMS) + (size_t)(t - 1) * DIMS + s * 16 + col] = yv;
        }
    }

    // ---- epilogue: y[T-1], h_last, c_last (all fp32) ----
    {
        const unsigned target = 16u * (unsigned)T_STEPS;
        while (budget > 0) {
            unsigned v = __hip_atomic_load(&flags[g], __ATOMIC_RELAXED, __HIP_MEMORY_SCOPE_AGENT);
            if (v >= target) break;
            --budget;
        }
        asm volatile("" ::: "memory");
        const unsigned long long* src = hbuf64 + (unsigned)(((T_STEPS - 1) & 1) * 16384)
                                        + (unsigned)(g * 16 + rS) * 256 + (unsigned)(tid & 15) * 16;
        unsigned long long v64[16];
        #pragma unroll
        for (int k = 0; k < 16; ++k)
            v64[k] = __hip_atomic_load(&src[k], __ATOMIC_RELAXED, __HIP_MEMORY_SCOPE_AGENT);
        unsigned long long* dh = reinterpret_cast<unsigned long long*>(&hsh[rS][cS32]);
        unsigned long long* dl = reinterpret_cast<unsigned long long*>(&hsl[rS][cS32]);
        #pragma unroll
        for (int m = 0; m < 8; ++m) {
            dh[m] = (unsigned long long)(unsigned)v64[2 * m]
                    | ((unsigned long long)(unsigned)v64[2 * m + 1] << 32);
            dl[m] = (unsigned long long)(unsigned)(v64[2 * m] >> 32)
                    | ((unsigned long long)(unsigned)(v64[2 * m + 1] >> 32) << 32);
        }
        __syncthreads();
        f32x4 yacc = {0.f, 0.f, 0.f, 0.f};
        #pragma unroll
        for (int q = 0; q < 4; ++q) {
            bf16x8 ah = *reinterpret_cast<const bf16x8*>(&hsh[lm][(wv * 4 + q) * 32 + quad * 8]);
            bf16x8 al = *reinterpret_cast<const bf16x8*>(&hsl[lm][(wv * 4 + q) * 32 + quad * 8]);
            yacc = __builtin_amdgcn_mfma_f32_16x16x32_bf16(ah, bWyh[q], yacc, 0, 0, 0);
            yacc = __builtin_amdgcn_mfma_f32_16x16x32_bf16(al, bWyh[q], yacc, 0, 0, 0);
            yacc = __builtin_amdgcn_mfma_f32_16x16x32_bf16(ah, bWyl[q], yacc, 0, 0, 0);
        }
        #pragma unroll
        for (int r = 0; r < 4; ++r) yp[wv][quad * 4 + r][lm] = yacc[r];
        __syncthreads();
        int row = tid >> 4, col = tid & 15;
        float yv = yp[0][row][col] + yp[1][row][col] + yp[2][row][col] + yp[3][row][col] + by;
        out[(size_t)(g * 16 + row) * (T_STEPS * DIMS) + (size_t)(T_STEPS - 1) * DIMS + s * 16 + col] = yv;

        const size_t YO = (size_t)64 * T_STEPS * DIMS;
        const size_t CO = YO + (size_t)64 * HID;
        #pragma unroll
        for (int d = 0; d < 2; ++d) {
            int u = uu + d;
            out[YO + (size_t)(g * 16 + rr) * HID + s * 32 + u] =
                bf2f(hsh[rr][s * 32 + u]) + bf2f(hsl[rr][s * 32 + u]);
            out[CO + (size_t)(g * 16 + rr) * HID + s * 32 + u] = cbuf[rr][u];
        }
    }
}

extern "C" void kernel_launch(void* const* d_in, const int* in_sizes, int n_in,
                              void* d_out, int out_size, void* d_ws, size_t ws_size,
                              hipStream_t stream) {
    const float* x  = (const float*)d_in[0];
    const float* h0 = (const float*)d_in[1];
    const float* c0 = (const float*)d_in[2];
    const float* Wj = (const float*)d_in[3];
    const float* Wi = (const float*)d_in[4];
    const float* Wf = (const float*)d_in[5];
    const float* Wo = (const float*)d_in[6];
    const float* Uj = (const float*)d_in[7];
    const float* Ui = (const float*)d_in[8];
    const float* Uf = (const float*)d_in[9];
    const float* Uo = (const float*)d_in[10];
    const float* bj = (const float*)d_in[11];
    const float* bi = (const float*)d_in[12];
    const float* bf = (const float*)d_in[13];
    const float* bo = (const float*)d_in[14];
    const float* Wy = (const float*)d_in[15];
    const float* by = (const float*)d_in[16];

    char* ws = (char*)d_ws;
    unsigned short* Uph = (unsigned short*)(ws + OFF_UHI);
    unsigned short* Upl = (unsigned short*)(ws + OFF_ULO);
    unsigned short* Wxh = (unsigned short*)(ws + OFF_WXHI);
    unsigned short* Wxl = (unsigned short*)(ws + OFF_WXLO);
    unsigned short* Wyh = (unsigned short*)(ws + OFF_WYHI);
    unsigned short* Wyl = (unsigned short*)(ws + OFF_WYLO);
    unsigned long long* hbuf64 = (unsigned long long*)(ws + OFF_HBUF);
    unsigned* flags     = (unsigned*)(ws + OFF_FLAGS);
    float* out          = (float*)d_out;

    int prep_total = NPACK_U + NPACK_WX + NPACK_WY + 64;
    int prep_blocks = (prep_total + 255) / 256;
    hipLaunchKernelGGL(lstm_prep, dim3(prep_blocks), dim3(256), 0, stream,
                       Uj, Ui, Uf, Uo, Wj, Wi, Wf, Wo, Wy,
                       Uph, Upl, Wxh, Wxl, Wyh, Wyl, flags);
    hipLaunchKernelGGL(lstm_scan, dim3(64), dim3(256), 0, stream,
                       x, h0, c0, bj, bi, bf, bo, by,
                       Uph, Upl, Wxh, Wxl, Wyh, Wyl, hbuf64, flags, out);
}

// Round 4
// 13153.888 us; speedup vs baseline: 1.0980x; 1.0980x over previous
//
#include <hip/hip_runtime.h>

// LSTM B=64, T=2048, D=256, H=512 — split-bf16 (hi+lo) compute, FP32 output.
// 64 WGs = 4 batch-groups (M=16) x 16 hidden-slices (32 hu each).
// Persistent kernel over 2048 steps; per-group epoch-counter sync per step.
// All GEMMs: A*B ~= Ah*Bh + Al*Bh + Ah*Bl (fp32 accum) -> ~fp32-accurate.
//
// R4 = R2 winner structure (bid = g*16+s, 2x u32 h exchange) +
//  - x(t+1) prefetch into VGPRs, issued AFTER the poll (poll loop never
//    waits on prefetch; HBM latency hides under Phase C/gates)
//  - publish store-ack hiding: h stores -> sched_barrier -> Phase D MFMAs
//    (independent) -> vmcnt(0) -> barrier -> flag add. The IF$ store RTT
//    overlaps the y-GEMM instead of stalling all 4 waves.
//  - y reduce/store after flag publish (off the inter-WG period)
// Reverted from R3: group->XCD swizzle (sync congestion through 2 XCD
// ports), u64 pack/unpack (VALU + VGPR pressure on critical path).

typedef __attribute__((ext_vector_type(8))) short bf16x8;
typedef __attribute__((ext_vector_type(4))) float f32x4;

#define T_STEPS 2048
#define DIMS 256
#define HID 512

#define NPACK_U  1048576
#define NPACK_WX 524288
#define NPACK_WY 131072

// workspace layout (bytes)
#define OFF_UHI   0u          // 2,097,152
#define OFF_ULO   2097152u    // 2,097,152
#define OFF_WXHI  4194304u    // 1,048,576
#define OFF_WXLO  5242880u    // 1,048,576
#define OFF_WYHI  6291456u    //   262,144
#define OFF_WYLO  6553600u    //   262,144
#define OFF_HBUF  6815744u    //   262,144 (2 parity x 2 half x 64 rows x 256 u32)
#define OFF_FLAGS 7077888u    //   64 u32 (only [0..3] used as epoch counters)

__device__ __forceinline__ unsigned short f2bf(float f) {
    unsigned u = __float_as_uint(f);
    return (unsigned short)((u + 0x7fffu + ((u >> 16) & 1u)) >> 16);
}
__device__ __forceinline__ float bf2f(unsigned short h) {
    return __uint_as_float((unsigned)h << 16);
}
__device__ __forceinline__ void split2(float f, unsigned short& hi, unsigned short& lo) {
    hi = f2bf(f);
    lo = f2bf(f - bf2f(hi));
}
__device__ __forceinline__ float sigf(float x) { return 1.0f / (1.0f + __expf(-x)); }
__device__ __forceinline__ float tanhfast(float x) { return 2.0f * sigf(2.0f * x) - 1.0f; }

// ---------------- prep: pack weights (hi+lo) into MFMA B-frag layout --------
// B-frag (16x16x32 bf16): lane l holds B[k = (l>>4)*8 + j][n = l&15], j=0..7.
__global__ void lstm_prep(const float* __restrict__ Uj, const float* __restrict__ Ui,
                          const float* __restrict__ Uf, const float* __restrict__ Uo,
                          const float* __restrict__ Wj, const float* __restrict__ Wi,
                          const float* __restrict__ Wf, const float* __restrict__ Wo,
                          const float* __restrict__ Wy,
                          unsigned short* __restrict__ Uph, unsigned short* __restrict__ Upl,
                          unsigned short* __restrict__ Wxh, unsigned short* __restrict__ Wxl,
                          unsigned short* __restrict__ Wyh, unsigned short* __restrict__ Wyl,
                          unsigned* __restrict__ flags) {
    int idx = blockIdx.x * 256 + threadIdx.x;
    if (idx < NPACK_U) {
        int j = idx & 7, l = (idx >> 3) & 63, ks = (idx >> 9) & 15, nt = (idx >> 13) & 7, s = (idx >> 16) & 15;
        int gate = nt >> 1;
        int hu = s * 32 + (nt & 1) * 16 + (l & 15);
        int k = ks * 32 + ((l >> 4) << 3) + j;
        const float* U = (gate == 0) ? Uj : (gate == 1) ? Ui : (gate == 2) ? Uf : Uo;
        unsigned short hi, lo; split2(U[k * HID + hu], hi, lo);
        Uph[idx] = hi; Upl[idx] = lo;
    } else if (idx < NPACK_U + NPACK_WX) {
        int i2 = idx - NPACK_U;
        int j = i2 & 7, l = (i2 >> 3) & 63, ks = (i2 >> 9) & 7, nt = (i2 >> 12) & 7, s = (i2 >> 15) & 15;
        int gate = nt >> 1;
        int hu = s * 32 + (nt & 1) * 16 + (l & 15);
        int k = ks * 32 + ((l >> 4) << 3) + j;
        const float* W = (gate == 0) ? Wj : (gate == 1) ? Wi : (gate == 2) ? Wf : Wo;
        unsigned short hi, lo; split2(W[k * HID + hu], hi, lo);
        Wxh[i2] = hi; Wxl[i2] = lo;
    } else if (idx < NPACK_U + NPACK_WX + NPACK_WY) {
        int i3 = idx - NPACK_U - NPACK_WX;
        int j = i3 & 7, l = (i3 >> 3) & 63, ks = (i3 >> 9) & 15, s = (i3 >> 13) & 15;
        int k = ks * 32 + ((l >> 4) << 3) + j;
        int col = s * 16 + (l & 15);
        unsigned short hi, lo; split2(Wy[k * DIMS + col], hi, lo);
        Wyh[i3] = hi; Wyl[i3] = lo;
    } else if (idx < NPACK_U + NPACK_WX + NPACK_WY + 64) {
        flags[idx - (NPACK_U + NPACK_WX + NPACK_WY)] = 0u;
    }
}

// ---------------- main persistent scan kernel -------------------------------
__global__ __launch_bounds__(256, 1) void lstm_scan(
    const float* __restrict__ x, const float* __restrict__ h0, const float* __restrict__ c0,
    const float* __restrict__ bj_g, const float* __restrict__ bi_g,
    const float* __restrict__ bf_g, const float* __restrict__ bo_g,
    const float* __restrict__ by_g,
    const unsigned short* __restrict__ Uph, const unsigned short* __restrict__ Upl,
    const unsigned short* __restrict__ Wxph, const unsigned short* __restrict__ Wxpl,
    const unsigned short* __restrict__ Wyph, const unsigned short* __restrict__ Wypl,
    unsigned* __restrict__ hbuf32, unsigned* __restrict__ flags,
    float* __restrict__ out)
{
    __shared__ unsigned short xsh[16][264];  // x_t hi (pitch 264)
    __shared__ unsigned short xsl[16][264];  // x_t lo
    __shared__ unsigned short hsh[16][520];  // h_{t-1} hi (pitch 520)
    __shared__ unsigned short hsl[16][520];  // h_{t-1} lo
    __shared__ float pre[8][16][17];         // gate pre-activations
    __shared__ float yp[4][16][17];          // y partials (per-wave K-split)
    __shared__ float cbuf[16][32];           // cell state (fp32, persistent)

    const int tid = threadIdx.x;
    const int wv = tid >> 6;
    const int l = tid & 63;
    const int quad = l >> 4;
    const int lm = l & 15;
    const int g = blockIdx.x >> 4;   // batch group
    const int s = blockIdx.x & 15;   // hidden slice

    // --- persistent B fragments in VGPRs (hi + lo) ---
    bf16x8 bUh[2][16], bUl[2][16], bWxh[2][8], bWxl[2][8], bWyh[4], bWyl[4];
    {
        const bf16x8* UH = reinterpret_cast<const bf16x8*>(Uph);
        const bf16x8* UL = reinterpret_cast<const bf16x8*>(Upl);
        const bf16x8* WH = reinterpret_cast<const bf16x8*>(Wxph);
        const bf16x8* WL = reinterpret_cast<const bf16x8*>(Wxpl);
        const bf16x8* YH = reinterpret_cast<const bf16x8*>(Wyph);
        const bf16x8* YL = reinterpret_cast<const bf16x8*>(Wypl);
        #pragma unroll
        for (int i = 0; i < 2; ++i) {
            int nt = 2 * wv + i;
            #pragma unroll
            for (int ks = 0; ks < 16; ++ks) {
                bUh[i][ks] = UH[((s * 8 + nt) * 16 + ks) * 64 + l];
                bUl[i][ks] = UL[((s * 8 + nt) * 16 + ks) * 64 + l];
            }
            #pragma unroll
            for (int ks = 0; ks < 8; ++ks) {
                bWxh[i][ks] = WH[((s * 8 + nt) * 8 + ks) * 64 + l];
                bWxl[i][ks] = WL[((s * 8 + nt) * 8 + ks) * 64 + l];
            }
        }
        #pragma unroll
        for (int q = 0; q < 4; ++q) {
            bWyh[q] = YH[(s * 16 + wv * 4 + q) * 64 + l];
            bWyl[q] = YL[(s * 16 + wv * 4 + q) * 64 + l];
        }
    }

    const int rr = tid >> 4;            // owned batch row
    const int uu = (tid & 15) * 2;      // owned local hidden units uu, uu+1
    cbuf[rr][uu]     = c0[(size_t)(g * 16 + rr) * HID + s * 32 + uu];
    cbuf[rr][uu + 1] = c0[(size_t)(g * 16 + rr) * HID + s * 32 + uu + 1];
    float bj0 = bj_g[s * 32 + uu], bj1 = bj_g[s * 32 + uu + 1];
    float bi0 = bi_g[s * 32 + uu], bi1 = bi_g[s * 32 + uu + 1];
    float bf0 = bf_g[s * 32 + uu], bf1 = bf_g[s * 32 + uu + 1];
    float bo0 = bo_g[s * 32 + uu], bo1 = bo_g[s * 32 + uu + 1];
    const float by = by_g[s * 16 + (tid & 15)];

    const int rS = tid >> 4;            // staging row
    const int cS16 = (tid & 15) * 16;   // x staging col (bf16 units)
    const int cS32 = (tid & 15) * 32;   // h staging col (bf16 units)
    long long budget = 1ll << 24;

    // --- prefetch x(0) into registers ---
    float4 xr[4];
    {
        const float4* xv = reinterpret_cast<const float4*>(
            x + (size_t)(g * 16 + rS) * (T_STEPS * DIMS) + cS16);
        xr[0] = xv[0]; xr[1] = xv[1]; xr[2] = xv[2]; xr[3] = xv[3];
    }

    __syncthreads();

    for (int t = 0; t < T_STEPS; ++t) {
        // ---- Phase A: stage x_t from prefetch regs (hi/lo split) ----
        {
            float4 f0 = xr[0], f1 = xr[1], f2 = xr[2], f3 = xr[3];
            uint4* xdh = reinterpret_cast<uint4*>(&xsh[rS][cS16]);
            uint4* xdl = reinterpret_cast<uint4*>(&xsl[rS][cS16]);
            unsigned short h0_, l0_, h1_, l1_, h2_, l2_, h3_, l3_;
            unsigned short h4_, l4_, h5_, l5_, h6_, l6_, h7_, l7_;
            uint4 uh, ul;
            split2(f0.x, h0_, l0_); split2(f0.y, h1_, l1_);
            split2(f0.z, h2_, l2_); split2(f0.w, h3_, l3_);
            split2(f1.x, h4_, l4_); split2(f1.y, h5_, l5_);
            split2(f1.z, h6_, l6_); split2(f1.w, h7_, l7_);
            uh.x = (unsigned)h0_ | ((unsigned)h1_ << 16);
            uh.y = (unsigned)h2_ | ((unsigned)h3_ << 16);
            uh.z = (unsigned)h4_ | ((unsigned)h5_ << 16);
            uh.w = (unsigned)h6_ | ((unsigned)h7_ << 16);
            ul.x = (unsigned)l0_ | ((unsigned)l1_ << 16);
            ul.y = (unsigned)l2_ | ((unsigned)l3_ << 16);
            ul.z = (unsigned)l4_ | ((unsigned)l5_ << 16);
            ul.w = (unsigned)l6_ | ((unsigned)l7_ << 16);
            xdh[0] = uh; xdl[0] = ul;
            split2(f2.x, h0_, l0_); split2(f2.y, h1_, l1_);
            split2(f2.z, h2_, l2_); split2(f2.w, h3_, l3_);
            split2(f3.x, h4_, l4_); split2(f3.y, h5_, l5_);
            split2(f3.z, h6_, l6_); split2(f3.w, h7_, l7_);
            uh.x = (unsigned)h0_ | ((unsigned)h1_ << 16);
            uh.y = (unsigned)h2_ | ((unsigned)h3_ << 16);
            uh.z = (unsigned)h4_ | ((unsigned)h5_ << 16);
            uh.w = (unsigned)h6_ | ((unsigned)h7_ << 16);
            ul.x = (unsigned)l0_ | ((unsigned)l1_ << 16);
            ul.y = (unsigned)l2_ | ((unsigned)l3_ << 16);
            ul.z = (unsigned)l4_ | ((unsigned)l5_ << 16);
            ul.w = (unsigned)l6_ | ((unsigned)l7_ << 16);
            xdh[1] = uh; xdl[1] = ul;
        }
        __syncthreads();
        f32x4 acc0 = {0.f, 0.f, 0.f, 0.f}, acc1 = {0.f, 0.f, 0.f, 0.f};
        #pragma unroll
        for (int ks = 0; ks < 8; ++ks) {
            bf16x8 ah = *reinterpret_cast<const bf16x8*>(&xsh[lm][ks * 32 + quad * 8]);
            bf16x8 al = *reinterpret_cast<const bf16x8*>(&xsl[lm][ks * 32 + quad * 8]);
            acc0 = __builtin_amdgcn_mfma_f32_16x16x32_bf16(ah, bWxh[0][ks], acc0, 0, 0, 0);
            acc0 = __builtin_amdgcn_mfma_f32_16x16x32_bf16(al, bWxh[0][ks], acc0, 0, 0, 0);
            acc0 = __builtin_amdgcn_mfma_f32_16x16x32_bf16(ah, bWxl[0][ks], acc0, 0, 0, 0);
            acc1 = __builtin_amdgcn_mfma_f32_16x16x32_bf16(ah, bWxh[1][ks], acc1, 0, 0, 0);
            acc1 = __builtin_amdgcn_mfma_f32_16x16x32_bf16(al, bWxh[1][ks], acc1, 0, 0, 0);
            acc1 = __builtin_amdgcn_mfma_f32_16x16x32_bf16(ah, bWxl[1][ks], acc1, 0, 0, 0);
        }

        // ---- Phase B: wait for peers' h[t-1]; prefetch x(t+1); load + stage ----
        if (t > 0) {
            const unsigned target = 16u * (unsigned)t;
            while (budget > 0) {
                unsigned v = __hip_atomic_load(&flags[g], __ATOMIC_RELAXED, __HIP_MEMORY_SCOPE_AGENT);
                if (v >= target) break;
                --budget;
            }
            asm volatile("" ::: "memory");   // data travels sc1, same path as poll
            // issue x(t+1) prefetch — consumed next Phase A; latency hides
            // under h-load + Phase C + gates.
            if (t + 1 < T_STEPS) {
                const float4* xv = reinterpret_cast<const float4*>(
                    x + (size_t)(g * 16 + rS) * (T_STEPS * DIMS) + (size_t)(t + 1) * DIMS + cS16);
                xr[0] = xv[0]; xr[1] = xv[1]; xr[2] = xv[2]; xr[3] = xv[3];
            }
            const unsigned base = (unsigned)(((t - 1) & 1) * 32768) + (unsigned)(g * 16 + rS) * 256
                                  + (unsigned)(tid & 15) * 16;
            const unsigned long long* sh = reinterpret_cast<const unsigned long long*>(hbuf32 + base);
            const unsigned long long* sl = reinterpret_cast<const unsigned long long*>(hbuf32 + 16384 + base);
            unsigned long long vh[8], vl[8];
            #pragma unroll
            for (int k = 0; k < 8; ++k)
                vh[k] = __hip_atomic_load(&sh[k], __ATOMIC_RELAXED, __HIP_MEMORY_SCOPE_AGENT);
            #pragma unroll
            for (int k = 0; k < 8; ++k)
                vl[k] = __hip_atomic_load(&sl[k], __ATOMIC_RELAXED, __HIP_MEMORY_SCOPE_AGENT);
            unsigned long long* dh = reinterpret_cast<unsigned long long*>(&hsh[rS][cS32]);
            unsigned long long* dl = reinterpret_cast<unsigned long long*>(&hsl[rS][cS32]);
            #pragma unroll
            for (int k = 0; k < 8; ++k) dh[k] = vh[k];
            #pragma unroll
            for (int k = 0; k < 8; ++k) dl[k] = vl[k];
        } else {
            const float4* xv = reinterpret_cast<const float4*>(
                x + (size_t)(g * 16 + rS) * (T_STEPS * DIMS) + (size_t)1 * DIMS + cS16);
            xr[0] = xv[0]; xr[1] = xv[1]; xr[2] = xv[2]; xr[3] = xv[3];
            const float4* hv = reinterpret_cast<const float4*>(
                h0 + (size_t)(g * 16 + rS) * HID + cS32);
            unsigned* hdh = reinterpret_cast<unsigned*>(&hsh[rS][cS32]);
            unsigned* hdl = reinterpret_cast<unsigned*>(&hsl[rS][cS32]);
            #pragma unroll
            for (int k = 0; k < 8; ++k) {
                float4 f = hv[k];
                unsigned short a0, b0, a1, b1, a2, b2, a3, b3;
                split2(f.x, a0, b0); split2(f.y, a1, b1);
                split2(f.z, a2, b2); split2(f.w, a3, b3);
                hdh[2 * k]     = (unsigned)a0 | ((unsigned)a1 << 16);
                hdh[2 * k + 1] = (unsigned)a2 | ((unsigned)a3 << 16);
                hdl[2 * k]     = (unsigned)b0 | ((unsigned)b1 << 16);
                hdl[2 * k + 1] = (unsigned)b2 | ((unsigned)b3 << 16);
            }
        }
        __syncthreads();

        // ---- Phase C: recurrent GEMM h[t-1] @ U_slice (3-pass split) ----
        #pragma unroll
        for (int ks = 0; ks < 16; ++ks) {
            bf16x8 ah = *reinterpret_cast<const bf16x8*>(&hsh[lm][ks * 32 + quad * 8]);
            bf16x8 al = *reinterpret_cast<const bf16x8*>(&hsl[lm][ks * 32 + quad * 8]);
            acc0 = __builtin_amdgcn_mfma_f32_16x16x32_bf16(ah, bUh[0][ks], acc0, 0, 0, 0);
            acc0 = __builtin_amdgcn_mfma_f32_16x16x32_bf16(al, bUh[0][ks], acc0, 0, 0, 0);
            acc0 = __builtin_amdgcn_mfma_f32_16x16x32_bf16(ah, bUl[0][ks], acc0, 0, 0, 0);
            acc1 = __builtin_amdgcn_mfma_f32_16x16x32_bf16(ah, bUh[1][ks], acc1, 0, 0, 0);
            acc1 = __builtin_amdgcn_mfma_f32_16x16x32_bf16(al, bUh[1][ks], acc1, 0, 0, 0);
            acc1 = __builtin_amdgcn_mfma_f32_16x16x32_bf16(ah, bUl[1][ks], acc1, 0, 0, 0);
        }
        #pragma unroll
        for (int r = 0; r < 4; ++r) {
            pre[2 * wv][quad * 4 + r][lm]     = acc0[r];
            pre[2 * wv + 1][quad * 4 + r][lm] = acc1[r];
        }
        __syncthreads();

        // ---- gates + cell update; publish h[t]; hide store-ack under D ----
        {
            unsigned short hh[2], hl[2];
            #pragma unroll
            for (int d = 0; d < 2; ++d) {
                int u = uu + d;
                int nt = u >> 4, cc = u & 15;
                float pj = pre[nt][rr][cc]     + (d ? bj1 : bj0);
                float pi = pre[2 + nt][rr][cc] + (d ? bi1 : bi0);
                float pf = pre[4 + nt][rr][cc] + (d ? bf1 : bf0);
                float po = pre[6 + nt][rr][cc] + (d ? bo1 : bo0);
                float jj = sigf(pj), ii = sigf(pi), ff = tanhfast(pf), oo = sigf(po);
                float cn = ff * cbuf[rr][u] + ii * jj;
                cbuf[rr][u] = cn;
                float hn = oo * tanhfast(cn);
                split2(hn, hh[d], hl[d]);
            }
            unsigned pkh = (unsigned)hh[0] | ((unsigned)hh[1] << 16);
            unsigned pkl = (unsigned)hl[0] | ((unsigned)hl[1] << 16);
            unsigned wbase = (unsigned)((t & 1) * 32768) + (unsigned)(g * 16 + rr) * 256
                             + (unsigned)s * 16 + (unsigned)(tid & 15);
            __hip_atomic_store(hbuf32 + wbase, pkh, __ATOMIC_RELAXED, __HIP_MEMORY_SCOPE_AGENT);
            __hip_atomic_store(hbuf32 + 16384 + wbase, pkl, __ATOMIC_RELAXED, __HIP_MEMORY_SCOPE_AGENT);
        }
        // pin the stores above Phase D so the MFMA cluster hides the ack RTT
        __builtin_amdgcn_sched_barrier(0);

        // ---- Phase D: y[t-1] = h[t-1] @ Wy_slice (hides store ack) ----
        f32x4 yacc = {0.f, 0.f, 0.f, 0.f};
        if (t > 0) {
            #pragma unroll
            for (int q = 0; q < 4; ++q) {
                bf16x8 ah = *reinterpret_cast<const bf16x8*>(&hsh[lm][(wv * 4 + q) * 32 + quad * 8]);
                bf16x8 al = *reinterpret_cast<const bf16x8*>(&hsl[lm][(wv * 4 + q) * 32 + quad * 8]);
                yacc = __builtin_amdgcn_mfma_f32_16x16x32_bf16(ah, bWyh[q], yacc, 0, 0, 0);
                yacc = __builtin_amdgcn_mfma_f32_16x16x32_bf16(al, bWyh[q], yacc, 0, 0, 0);
                yacc = __builtin_amdgcn_mfma_f32_16x16x32_bf16(ah, bWyl[q], yacc, 0, 0, 0);
            }
            #pragma unroll
            for (int r = 0; r < 4; ++r) yp[wv][quad * 4 + r][lm] = yacc[r];
        }
        // sc1 stores are IF$-bound; vmcnt(0) == "data visible at coherence point"
        asm volatile("s_waitcnt vmcnt(0)" ::: "memory");
        __syncthreads();   // all waves acked (+ yp visible)
        if (tid == 0)
            (void)__hip_atomic_fetch_add(&flags[g], 1u, __ATOMIC_RELAXED, __HIP_MEMORY_SCOPE_AGENT);

        // ---- y finalize (off the inter-WG critical path) ----
        if (t > 0) {
            int row = tid >> 4, col = tid & 15;
            float yv = yp[0][row][col] + yp[1][row][col] + yp[2][row][col] + yp[3][row][col] + by;
            out[(size_t)(g * 16 + row) * (T_STEPS * DIMS) + (size_t)(t - 1) * DIMS + s * 16 + col] = yv;
        }
    }

    // ---- epilogue: y[T-1], h_last, c_last (all fp32) ----
    {
        const unsigned target = 16u * (unsigned)T_STEPS;
        while (budget > 0) {
            unsigned v = __hip_atomic_load(&flags[g], __ATOMIC_RELAXED, __HIP_MEMORY_SCOPE_AGENT);
            if (v >= target) break;
            --budget;
        }
        asm volatile("" ::: "memory");
        const unsigned base = (unsigned)(((T_STEPS - 1) & 1) * 32768) + (unsigned)(g * 16 + rS) * 256
                              + (unsigned)(tid & 15) * 16;
        const unsigned long long* sh = reinterpret_cast<const unsigned long long*>(hbuf32 + base);
        const unsigned long long* sl = reinterpret_cast<const unsigned long long*>(hbuf32 + 16384 + base);
        unsigned long long vh[8], vl[8];
        #pragma unroll
        for (int k = 0; k < 8; ++k)
            vh[k] = __hip_atomic_load(&sh[k], __ATOMIC_RELAXED, __HIP_MEMORY_SCOPE_AGENT);
        #pragma unroll
        for (int k = 0; k < 8; ++k)
            vl[k] = __hip_atomic_load(&sl[k], __ATOMIC_RELAXED, __HIP_MEMORY_SCOPE_AGENT);
        unsigned long long* dh = reinterpret_cast<unsigned long long*>(&hsh[rS][cS32]);
        unsigned long long* dl = reinterpret_cast<unsigned long long*>(&hsl[rS][cS32]);
        #pragma unroll
        for (int k = 0; k < 8; ++k) dh[k] = vh[k];
        #pragma unroll
        for (int k = 0; k < 8; ++k) dl[k] = vl[k];
        __syncthreads();
        f32x4 yacc = {0.f, 0.f, 0.f, 0.f};
        #pragma unroll
        for (int q = 0; q < 4; ++q) {
            bf16x8 ah = *reinterpret_cast<const bf16x8*>(&hsh[lm][(wv * 4 + q) * 32 + quad * 8]);
            bf16x8 al = *reinterpret_cast<const bf16x8*>(&hsl[lm][(wv * 4 + q) * 32 + quad * 8]);
            yacc = __builtin_amdgcn_mfma_f32_16x16x32_bf16(ah, bWyh[q], yacc, 0, 0, 0);
            yacc = __builtin_amdgcn_mfma_f32_16x16x32_bf16(al, bWyh[q], yacc, 0, 0, 0);
            yacc = __builtin_amdgcn_mfma_f32_16x16x32_bf16(ah, bWyl[q], yacc, 0, 0, 0);
        }
        #pragma unroll
        for (int r = 0; r < 4; ++r) yp[wv][quad * 4 + r][lm] = yacc[r];
        __syncthreads();
        int row = tid >> 4, col = tid & 15;
        float yv = yp[0][row][col] + yp[1][row][col] + yp[2][row][col] + yp[3][row][col] + by;
        out[(size_t)(g * 16 + row) * (T_STEPS * DIMS) + (size_t)(T_STEPS - 1) * DIMS + s * 16 + col] = yv;

        const size_t YO = (size_t)64 * T_STEPS * DIMS;
        const size_t CO = YO + (size_t)64 * HID;
        #pragma unroll
        for (int d = 0; d < 2; ++d) {
            int u = uu + d;
            out[YO + (size_t)(g * 16 + rr) * HID + s * 32 + u] =
                bf2f(hsh[rr][s * 32 + u]) + bf2f(hsl[rr][s * 32 + u]);
            out[CO + (size_t)(g * 16 + rr) * HID + s * 32 + u] = cbuf[rr][u];
        }
    }
}

extern "C" void kernel_launch(void* const* d_in, const int* in_sizes, int n_in,
                              void* d_out, int out_size, void* d_ws, size_t ws_size,
                              hipStream_t stream) {
    const float* x  = (const float*)d_in[0];
    const float* h0 = (const float*)d_in[1];
    const float* c0 = (const float*)d_in[2];
    const float* Wj = (const float*)d_in[3];
    const float* Wi = (const float*)d_in[4];
    const float* Wf = (const float*)d_in[5];
    const float* Wo = (const float*)d_in[6];
    const float* Uj = (const float*)d_in[7];
    const float* Ui = (const float*)d_in[8];
    const float* Uf = (const float*)d_in[9];
    const float* Uo = (const float*)d_in[10];
    const float* bj = (const float*)d_in[11];
    const float* bi = (const float*)d_in[12];
    const float* bf = (const float*)d_in[13];
    const float* bo = (const float*)d_in[14];
    const float* Wy = (const float*)d_in[15];
    const float* by = (const float*)d_in[16];

    char* ws = (char*)d_ws;
    unsigned short* Uph = (unsigned short*)(ws + OFF_UHI);
    unsigned short* Upl = (unsigned short*)(ws + OFF_ULO);
    unsigned short* Wxh = (unsigned short*)(ws + OFF_WXHI);
    unsigned short* Wxl = (unsigned short*)(ws + OFF_WXLO);
    unsigned short* Wyh = (unsigned short*)(ws + OFF_WYHI);
    unsigned short* Wyl = (unsigned short*)(ws + OFF_WYLO);
    unsigned* hbuf32    = (unsigned*)(ws + OFF_HBUF);
    unsigned* flags     = (unsigned*)(ws + OFF_FLAGS);
    float* out          = (float*)d_out;

    int prep_total = NPACK_U + NPACK_WX + NPACK_WY + 64;
    int prep_blocks = (prep_total + 255) / 256;
    hipLaunchKernelGGL(lstm_prep, dim3(prep_blocks), dim3(256), 0, stream,
                       Uj, Ui, Uf, Uo, Wj, Wi, Wf, Wo, Wy,
                       Uph, Upl, Wxh, Wxl, Wyh, Wyl, flags);
    hipLaunchKernelGGL(lstm_scan, dim3(64), dim3(256), 0, stream,
                       x, h0, c0, bj, bi, bf, bo, by,
                       Uph, Upl, Wxh, Wxl, Wyh, Wyl, hbuf32, flags, out);
}

// Round 5
// 12031.845 us; speedup vs baseline: 1.2004x; 1.0933x over previous
//
#include <hip/hip_runtime.h>

// LSTM B=64, T=2048, D=256, H=512 — split-bf16 (hi+lo) compute, FP32 output.
// 64 WGs = 4 batch-groups (M=16) x 16 hidden-slices (32 hu each).
// Persistent kernel over 2048 steps; per-group per-slice flag sync per step.
// All GEMMs: A*B ~= Ah*Bh + Al*Bh + Ah*Bl (fp32 accum) -> ~fp32-accurate.
//
// R5 = R2 structure exactly (best measured: 12.66 ms), ONE change:
//  - sync: single atomicAdd epoch counter -> 16 per-slice PLAIN relaxed
//    stores into one 64B line (flags[g*16+s] = t+1). Removes the 16-deep
//    RMW convoy at the IF$ bank from the publish tail; poll = 16 lanes
//    load one line + __all (same read cost as before).
// Reverted from R4: Phase D between store and publish (added its duration
// to the critical chain, +0.4ms), x-prefetch (neutral, removed for purity).

typedef __attribute__((ext_vector_type(8))) short bf16x8;
typedef __attribute__((ext_vector_type(4))) float f32x4;

#define T_STEPS 2048
#define DIMS 256
#define HID 512

#define NPACK_U  1048576
#define NPACK_WX 524288
#define NPACK_WY 131072

// workspace layout (bytes)
#define OFF_UHI   0u          // 2,097,152
#define OFF_ULO   2097152u    // 2,097,152
#define OFF_WXHI  4194304u    // 1,048,576
#define OFF_WXLO  5242880u    // 1,048,576
#define OFF_WYHI  6291456u    //   262,144
#define OFF_WYLO  6553600u    //   262,144
#define OFF_HBUF  6815744u    //   262,144 (2 parity x 2 half x 64 rows x 256 u32)
#define OFF_FLAGS 7077888u    //   64 u32 (per-group 16 per-slice flags, one line)

__device__ __forceinline__ unsigned short f2bf(float f) {
    unsigned u = __float_as_uint(f);
    return (unsigned short)((u + 0x7fffu + ((u >> 16) & 1u)) >> 16);
}
__device__ __forceinline__ float bf2f(unsigned short h) {
    return __uint_as_float((unsigned)h << 16);
}
__device__ __forceinline__ void split2(float f, unsigned short& hi, unsigned short& lo) {
    hi = f2bf(f);
    lo = f2bf(f - bf2f(hi));
}
__device__ __forceinline__ float sigf(float x) { return 1.0f / (1.0f + __expf(-x)); }
__device__ __forceinline__ float tanhfast(float x) { return 2.0f * sigf(2.0f * x) - 1.0f; }

// ---------------- prep: pack weights (hi+lo) into MFMA B-frag layout --------
// B-frag (16x16x32 bf16): lane l holds B[k = (l>>4)*8 + j][n = l&15], j=0..7.
__global__ void lstm_prep(const float* __restrict__ Uj, const float* __restrict__ Ui,
                          const float* __restrict__ Uf, const float* __restrict__ Uo,
                          const float* __restrict__ Wj, const float* __restrict__ Wi,
                          const float* __restrict__ Wf, const float* __restrict__ Wo,
                          const float* __restrict__ Wy,
                          unsigned short* __restrict__ Uph, unsigned short* __restrict__ Upl,
                          unsigned short* __restrict__ Wxh, unsigned short* __restrict__ Wxl,
                          unsigned short* __restrict__ Wyh, unsigned short* __restrict__ Wyl,
                          unsigned* __restrict__ flags) {
    int idx = blockIdx.x * 256 + threadIdx.x;
    if (idx < NPACK_U) {
        int j = idx & 7, l = (idx >> 3) & 63, ks = (idx >> 9) & 15, nt = (idx >> 13) & 7, s = (idx >> 16) & 15;
        int gate = nt >> 1;
        int hu = s * 32 + (nt & 1) * 16 + (l & 15);
        int k = ks * 32 + ((l >> 4) << 3) + j;
        const float* U = (gate == 0) ? Uj : (gate == 1) ? Ui : (gate == 2) ? Uf : Uo;
        unsigned short hi, lo; split2(U[k * HID + hu], hi, lo);
        Uph[idx] = hi; Upl[idx] = lo;
    } else if (idx < NPACK_U + NPACK_WX) {
        int i2 = idx - NPACK_U;
        int j = i2 & 7, l = (i2 >> 3) & 63, ks = (i2 >> 9) & 7, nt = (i2 >> 12) & 7, s = (i2 >> 15) & 15;
        int gate = nt >> 1;
        int hu = s * 32 + (nt & 1) * 16 + (l & 15);
        int k = ks * 32 + ((l >> 4) << 3) + j;
        const float* W = (gate == 0) ? Wj : (gate == 1) ? Wi : (gate == 2) ? Wf : Wo;
        unsigned short hi, lo; split2(W[k * HID + hu], hi, lo);
        Wxh[i2] = hi; Wxl[i2] = lo;
    } else if (idx < NPACK_U + NPACK_WX + NPACK_WY) {
        int i3 = idx - NPACK_U - NPACK_WX;
        int j = i3 & 7, l = (i3 >> 3) & 63, ks = (i3 >> 9) & 15, s = (i3 >> 13) & 15;
        int k = ks * 32 + ((l >> 4) << 3) + j;
        int col = s * 16 + (l & 15);
        unsigned short hi, lo; split2(Wy[k * DIMS + col], hi, lo);
        Wyh[i3] = hi; Wyl[i3] = lo;
    } else if (idx < NPACK_U + NPACK_WX + NPACK_WY + 64) {
        flags[idx - (NPACK_U + NPACK_WX + NPACK_WY)] = 0u;
    }
}

// ---------------- main persistent scan kernel -------------------------------
__global__ __launch_bounds__(256, 1) void lstm_scan(
    const float* __restrict__ x, const float* __restrict__ h0, const float* __restrict__ c0,
    const float* __restrict__ bj_g, const float* __restrict__ bi_g,
    const float* __restrict__ bf_g, const float* __restrict__ bo_g,
    const float* __restrict__ by_g,
    const unsigned short* __restrict__ Uph, const unsigned short* __restrict__ Upl,
    const unsigned short* __restrict__ Wxph, const unsigned short* __restrict__ Wxpl,
    const unsigned short* __restrict__ Wyph, const unsigned short* __restrict__ Wypl,
    unsigned* __restrict__ hbuf32, unsigned* __restrict__ flags,
    float* __restrict__ out)
{
    __shared__ unsigned short xsh[16][264];  // x_t hi (pitch 264)
    __shared__ unsigned short xsl[16][264];  // x_t lo
    __shared__ unsigned short hsh[16][520];  // h_{t-1} hi (pitch 520)
    __shared__ unsigned short hsl[16][520];  // h_{t-1} lo
    __shared__ float pre[8][16][17];         // gate pre-activations
    __shared__ float yp[4][16][17];          // y partials (per-wave K-split)
    __shared__ float cbuf[16][32];           // cell state (fp32, persistent)

    const int tid = threadIdx.x;
    const int wv = tid >> 6;
    const int l = tid & 63;
    const int quad = l >> 4;
    const int lm = l & 15;
    const int g = blockIdx.x >> 4;   // batch group
    const int s = blockIdx.x & 15;   // hidden slice

    // --- persistent B fragments in VGPRs (hi + lo) ---
    bf16x8 bUh[2][16], bUl[2][16], bWxh[2][8], bWxl[2][8], bWyh[4], bWyl[4];
    {
        const bf16x8* UH = reinterpret_cast<const bf16x8*>(Uph);
        const bf16x8* UL = reinterpret_cast<const bf16x8*>(Upl);
        const bf16x8* WH = reinterpret_cast<const bf16x8*>(Wxph);
        const bf16x8* WL = reinterpret_cast<const bf16x8*>(Wxpl);
        const bf16x8* YH = reinterpret_cast<const bf16x8*>(Wyph);
        const bf16x8* YL = reinterpret_cast<const bf16x8*>(Wypl);
        #pragma unroll
        for (int i = 0; i < 2; ++i) {
            int nt = 2 * wv + i;
            #pragma unroll
            for (int ks = 0; ks < 16; ++ks) {
                bUh[i][ks] = UH[((s * 8 + nt) * 16 + ks) * 64 + l];
                bUl[i][ks] = UL[((s * 8 + nt) * 16 + ks) * 64 + l];
            }
            #pragma unroll
            for (int ks = 0; ks < 8; ++ks) {
                bWxh[i][ks] = WH[((s * 8 + nt) * 8 + ks) * 64 + l];
                bWxl[i][ks] = WL[((s * 8 + nt) * 8 + ks) * 64 + l];
            }
        }
        #pragma unroll
        for (int q = 0; q < 4; ++q) {
            bWyh[q] = YH[(s * 16 + wv * 4 + q) * 64 + l];
            bWyl[q] = YL[(s * 16 + wv * 4 + q) * 64 + l];
        }
    }

    const int rr = tid >> 4;            // owned batch row
    const int uu = (tid & 15) * 2;      // owned local hidden units uu, uu+1
    cbuf[rr][uu]     = c0[(size_t)(g * 16 + rr) * HID + s * 32 + uu];
    cbuf[rr][uu + 1] = c0[(size_t)(g * 16 + rr) * HID + s * 32 + uu + 1];
    float bj0 = bj_g[s * 32 + uu], bj1 = bj_g[s * 32 + uu + 1];
    float bi0 = bi_g[s * 32 + uu], bi1 = bi_g[s * 32 + uu + 1];
    float bf0 = bf_g[s * 32 + uu], bf1 = bf_g[s * 32 + uu + 1];
    float bo0 = bo_g[s * 32 + uu], bo1 = bo_g[s * 32 + uu + 1];
    const float by = by_g[s * 16 + (tid & 15)];

    const int rS = tid >> 4;            // staging row
    const int cS16 = (tid & 15) * 16;   // x staging col (bf16 units)
    const int cS32 = (tid & 15) * 32;   // h staging col (bf16 units)
    long long budget = 1ll << 24;

    __syncthreads();

    for (int t = 0; t < T_STEPS; ++t) {
        // ---- Phase A: stage x_t split (vectorized), then x-projection MFMAs ----
        {
            const float4* xv = reinterpret_cast<const float4*>(
                x + (size_t)(g * 16 + rS) * (T_STEPS * DIMS) + (size_t)t * DIMS + cS16);
            uint4* xdh = reinterpret_cast<uint4*>(&xsh[rS][cS16]);
            uint4* xdl = reinterpret_cast<uint4*>(&xsl[rS][cS16]);
            #pragma unroll
            for (int k = 0; k < 2; ++k) {
                float4 fa = xv[2 * k], fb = xv[2 * k + 1];
                unsigned short h0_, l0_, h1_, l1_, h2_, l2_, h3_, l3_;
                unsigned short h4_, l4_, h5_, l5_, h6_, l6_, h7_, l7_;
                split2(fa.x, h0_, l0_); split2(fa.y, h1_, l1_);
                split2(fa.z, h2_, l2_); split2(fa.w, h3_, l3_);
                split2(fb.x, h4_, l4_); split2(fb.y, h5_, l5_);
                split2(fb.z, h6_, l6_); split2(fb.w, h7_, l7_);
                uint4 uh, ul;
                uh.x = (unsigned)h0_ | ((unsigned)h1_ << 16);
                uh.y = (unsigned)h2_ | ((unsigned)h3_ << 16);
                uh.z = (unsigned)h4_ | ((unsigned)h5_ << 16);
                uh.w = (unsigned)h6_ | ((unsigned)h7_ << 16);
                ul.x = (unsigned)l0_ | ((unsigned)l1_ << 16);
                ul.y = (unsigned)l2_ | ((unsigned)l3_ << 16);
                ul.z = (unsigned)l4_ | ((unsigned)l5_ << 16);
                ul.w = (unsigned)l6_ | ((unsigned)l7_ << 16);
                xdh[k] = uh; xdl[k] = ul;
            }
        }
        __syncthreads();
        f32x4 acc0 = {0.f, 0.f, 0.f, 0.f}, acc1 = {0.f, 0.f, 0.f, 0.f};
        #pragma unroll
        for (int ks = 0; ks < 8; ++ks) {
            bf16x8 ah = *reinterpret_cast<const bf16x8*>(&xsh[lm][ks * 32 + quad * 8]);
            bf16x8 al = *reinterpret_cast<const bf16x8*>(&xsl[lm][ks * 32 + quad * 8]);
            acc0 = __builtin_amdgcn_mfma_f32_16x16x32_bf16(ah, bWxh[0][ks], acc0, 0, 0, 0);
            acc0 = __builtin_amdgcn_mfma_f32_16x16x32_bf16(al, bWxh[0][ks], acc0, 0, 0, 0);
            acc0 = __builtin_amdgcn_mfma_f32_16x16x32_bf16(ah, bWxl[0][ks], acc0, 0, 0, 0);
            acc1 = __builtin_amdgcn_mfma_f32_16x16x32_bf16(ah, bWxh[1][ks], acc1, 0, 0, 0);
            acc1 = __builtin_amdgcn_mfma_f32_16x16x32_bf16(al, bWxh[1][ks], acc1, 0, 0, 0);
            acc1 = __builtin_amdgcn_mfma_f32_16x16x32_bf16(ah, bWxl[1][ks], acc1, 0, 0, 0);
        }

        // ---- Phase B: wait for peers' h[t-1] (per-slice flags), load + stage ----
        if (t > 0) {
            const unsigned target = (unsigned)t;
            while (budget > 0) {
                unsigned v = (l < 16)
                    ? __hip_atomic_load(&flags[g * 16 + l], __ATOMIC_RELAXED, __HIP_MEMORY_SCOPE_AGENT)
                    : target;
                if (__all((int)(v >= target))) break;
                --budget;
            }
            asm volatile("" ::: "memory");   // data travels sc1, same path as poll
            const unsigned base = (unsigned)(((t - 1) & 1) * 32768) + (unsigned)(g * 16 + rS) * 256
                                  + (unsigned)(tid & 15) * 16;
            const unsigned long long* sh = reinterpret_cast<const unsigned long long*>(hbuf32 + base);
            const unsigned long long* sl = reinterpret_cast<const unsigned long long*>(hbuf32 + 16384 + base);
            unsigned long long vh[8], vl[8];
            #pragma unroll
            for (int k = 0; k < 8; ++k)
                vh[k] = __hip_atomic_load(&sh[k], __ATOMIC_RELAXED, __HIP_MEMORY_SCOPE_AGENT);
            #pragma unroll
            for (int k = 0; k < 8; ++k)
                vl[k] = __hip_atomic_load(&sl[k], __ATOMIC_RELAXED, __HIP_MEMORY_SCOPE_AGENT);
            unsigned long long* dh = reinterpret_cast<unsigned long long*>(&hsh[rS][cS32]);
            unsigned long long* dl = reinterpret_cast<unsigned long long*>(&hsl[rS][cS32]);
            #pragma unroll
            for (int k = 0; k < 8; ++k) dh[k] = vh[k];
            #pragma unroll
            for (int k = 0; k < 8; ++k) dl[k] = vl[k];
        } else {
            const float4* hv = reinterpret_cast<const float4*>(
                h0 + (size_t)(g * 16 + rS) * HID + cS32);
            unsigned* hdh = reinterpret_cast<unsigned*>(&hsh[rS][cS32]);
            unsigned* hdl = reinterpret_cast<unsigned*>(&hsl[rS][cS32]);
            #pragma unroll
            for (int k = 0; k < 8; ++k) {
                float4 f = hv[k];
                unsigned short a0, b0, a1, b1, a2, b2, a3, b3;
                split2(f.x, a0, b0); split2(f.y, a1, b1);
                split2(f.z, a2, b2); split2(f.w, a3, b3);
                hdh[2 * k]     = (unsigned)a0 | ((unsigned)a1 << 16);
                hdh[2 * k + 1] = (unsigned)a2 | ((unsigned)a3 << 16);
                hdl[2 * k]     = (unsigned)b0 | ((unsigned)b1 << 16);
                hdl[2 * k + 1] = (unsigned)b2 | ((unsigned)b3 << 16);
            }
        }
        __syncthreads();

        // ---- Phase C: recurrent GEMM h[t-1] @ U_slice (3-pass split) ----
        #pragma unroll
        for (int ks = 0; ks < 16; ++ks) {
            bf16x8 ah = *reinterpret_cast<const bf16x8*>(&hsh[lm][ks * 32 + quad * 8]);
            bf16x8 al = *reinterpret_cast<const bf16x8*>(&hsl[lm][ks * 32 + quad * 8]);
            acc0 = __builtin_amdgcn_mfma_f32_16x16x32_bf16(ah, bUh[0][ks], acc0, 0, 0, 0);
            acc0 = __builtin_amdgcn_mfma_f32_16x16x32_bf16(al, bUh[0][ks], acc0, 0, 0, 0);
            acc0 = __builtin_amdgcn_mfma_f32_16x16x32_bf16(ah, bUl[0][ks], acc0, 0, 0, 0);
            acc1 = __builtin_amdgcn_mfma_f32_16x16x32_bf16(ah, bUh[1][ks], acc1, 0, 0, 0);
            acc1 = __builtin_amdgcn_mfma_f32_16x16x32_bf16(al, bUh[1][ks], acc1, 0, 0, 0);
            acc1 = __builtin_amdgcn_mfma_f32_16x16x32_bf16(ah, bUl[1][ks], acc1, 0, 0, 0);
        }
        // ---- Phase D: y[t-1] = h[t-1] @ Wy_slice (K split across waves) ----
        f32x4 yacc = {0.f, 0.f, 0.f, 0.f};
        if (t > 0) {
            #pragma unroll
            for (int q = 0; q < 4; ++q) {
                bf16x8 ah = *reinterpret_cast<const bf16x8*>(&hsh[lm][(wv * 4 + q) * 32 + quad * 8]);
                bf16x8 al = *reinterpret_cast<const bf16x8*>(&hsl[lm][(wv * 4 + q) * 32 + quad * 8]);
                yacc = __builtin_amdgcn_mfma_f32_16x16x32_bf16(ah, bWyh[q], yacc, 0, 0, 0);
                yacc = __builtin_amdgcn_mfma_f32_16x16x32_bf16(al, bWyh[q], yacc, 0, 0, 0);
                yacc = __builtin_amdgcn_mfma_f32_16x16x32_bf16(ah, bWyl[q], yacc, 0, 0, 0);
            }
        }
        #pragma unroll
        for (int r = 0; r < 4; ++r) {
            pre[2 * wv][quad * 4 + r][lm]     = acc0[r];
            pre[2 * wv + 1][quad * 4 + r][lm] = acc1[r];
            yp[wv][quad * 4 + r][lm]          = yacc[r];
        }
        __syncthreads();

        // ---- gates + cell update; publish h[t] (hi|lo) FIRST ----
        {
            unsigned short hh[2], hl[2];
            #pragma unroll
            for (int d = 0; d < 2; ++d) {
                int u = uu + d;
                int nt = u >> 4, cc = u & 15;
                float pj = pre[nt][rr][cc]     + (d ? bj1 : bj0);
                float pi = pre[2 + nt][rr][cc] + (d ? bi1 : bi0);
                float pf = pre[4 + nt][rr][cc] + (d ? bf1 : bf0);
                float po = pre[6 + nt][rr][cc] + (d ? bo1 : bo0);
                float jj = sigf(pj), ii = sigf(pi), ff = tanhfast(pf), oo = sigf(po);
                float cn = ff * cbuf[rr][u] + ii * jj;
                cbuf[rr][u] = cn;
                float hn = oo * tanhfast(cn);
                split2(hn, hh[d], hl[d]);
            }
            unsigned pkh = (unsigned)hh[0] | ((unsigned)hh[1] << 16);
            unsigned pkl = (unsigned)hl[0] | ((unsigned)hl[1] << 16);
            unsigned wbase = (unsigned)((t & 1) * 32768) + (unsigned)(g * 16 + rr) * 256
                             + (unsigned)s * 16 + (unsigned)(tid & 15);
            __hip_atomic_store(hbuf32 + wbase, pkh, __ATOMIC_RELAXED, __HIP_MEMORY_SCOPE_AGENT);
            __hip_atomic_store(hbuf32 + 16384 + wbase, pkl, __ATOMIC_RELAXED, __HIP_MEMORY_SCOPE_AGENT);
        }
        // sc1 stores are IF$-bound; vmcnt(0) == "data visible at coherence point"
        asm volatile("s_waitcnt vmcnt(0)" ::: "memory");
        __syncthreads();
        if (tid == 0)
            __hip_atomic_store(&flags[g * 16 + s], (unsigned)(t + 1),
                               __ATOMIC_RELAXED, __HIP_MEMORY_SCOPE_AGENT);

        // ---- y finalize (off the inter-WG critical path) ----
        if (t > 0) {
            int row = tid >> 4, col = tid & 15;
            float yv = yp[0][row][col] + yp[1][row][col] + yp[2][row][col] + yp[3][row][col] + by;
            out[(size_t)(g * 16 + row) * (T_STEPS * DIMS) + (size_t)(t - 1) * DIMS + s * 16 + col] = yv;
        }
    }

    // ---- epilogue: y[T-1], h_last, c_last (all fp32) ----
    {
        const unsigned target = (unsigned)T_STEPS;
        while (budget > 0) {
            unsigned v = (l < 16)
                ? __hip_atomic_load(&flags[g * 16 + l], __ATOMIC_RELAXED, __HIP_MEMORY_SCOPE_AGENT)
                : target;
            if (__all((int)(v >= target))) break;
            --budget;
        }
        asm volatile("" ::: "memory");
        const unsigned base = (unsigned)(((T_STEPS - 1) & 1) * 32768) + (unsigned)(g * 16 + rS) * 256
                              + (unsigned)(tid & 15) * 16;
        const unsigned long long* sh = reinterpret_cast<const unsigned long long*>(hbuf32 + base);
        const unsigned long long* sl = reinterpret_cast<const unsigned long long*>(hbuf32 + 16384 + base);
        unsigned long long vh[8], vl[8];
        #pragma unroll
        for (int k = 0; k < 8; ++k)
            vh[k] = __hip_atomic_load(&sh[k], __ATOMIC_RELAXED, __HIP_MEMORY_SCOPE_AGENT);
        #pragma unroll
        for (int k = 0; k < 8; ++k)
            vl[k] = __hip_atomic_load(&sl[k], __ATOMIC_RELAXED, __HIP_MEMORY_SCOPE_AGENT);
        unsigned long long* dh = reinterpret_cast<unsigned long long*>(&hsh[rS][cS32]);
        unsigned long long* dl = reinterpret_cast<unsigned long long*>(&hsl[rS][cS32]);
        #pragma unroll
        for (int k = 0; k < 8; ++k) dh[k] = vh[k];
        #pragma unroll
        for (int k = 0; k < 8; ++k) dl[k] = vl[k];
        __syncthreads();
        f32x4 yacc = {0.f, 0.f, 0.f, 0.f};
        #pragma unroll
        for (int q = 0; q < 4; ++q) {
            bf16x8 ah = *reinterpret_cast<const bf16x8*>(&hsh[lm][(wv * 4 + q) * 32 + quad * 8]);
            bf16x8 al = *reinterpret_cast<const bf16x8*>(&hsl[lm][(wv * 4 + q) * 32 + quad * 8]);
            yacc = __builtin_amdgcn_mfma_f32_16x16x32_bf16(ah, bWyh[q], yacc, 0, 0, 0);
            yacc = __builtin_amdgcn_mfma_f32_16x16x32_bf16(al, bWyh[q], yacc, 0, 0, 0);
            yacc = __builtin_amdgcn_mfma_f32_16x16x32_bf16(ah, bWyl[q], yacc, 0, 0, 0);
        }
        #pragma unroll
        for (int r = 0; r < 4; ++r) yp[wv][quad * 4 + r][lm] = yacc[r];
        __syncthreads();
        int row = tid >> 4, col = tid & 15;
        float yv = yp[0][row][col] + yp[1][row][col] + yp[2][row][col] + yp[3][row][col] + by;
        out[(size_t)(g * 16 + row) * (T_STEPS * DIMS) + (size_t)(T_STEPS - 1) * DIMS + s * 16 + col] = yv;

        const size_t YO = (size_t)64 * T_STEPS * DIMS;
        const size_t CO = YO + (size_t)64 * HID;
        #pragma unroll
        for (int d = 0; d < 2; ++d) {
            int u = uu + d;
            out[YO + (size_t)(g * 16 + rr) * HID + s * 32 + u] =
                bf2f(hsh[rr][s * 32 + u]) + bf2f(hsl[rr][s * 32 + u]);
            out[CO + (size_t)(g * 16 + rr) * HID + s * 32 + u] = cbuf[rr][u];
        }
    }
}

extern "C" void kernel_launch(void* const* d_in, const int* in_sizes, int n_in,
                              void* d_out, int out_size, void* d_ws, size_t ws_size,
                              hipStream_t stream) {
    const float* x  = (const float*)d_in[0];
    const float* h0 = (const float*)d_in[1];
    const float* c0 = (const float*)d_in[2];
    const float* Wj = (const float*)d_in[3];
    const float* Wi = (const float*)d_in[4];
    const float* Wf = (const float*)d_in[5];
    const float* Wo = (const float*)d_in[6];
    const float* Uj = (const float*)d_in[7];
    const float* Ui = (const float*)d_in[8];
    const float* Uf = (const float*)d_in[9];
    const float* Uo = (const float*)d_in[10];
    const float* bj = (const float*)d_in[11];
    const float* bi = (const float*)d_in[12];
    const float* bf = (const float*)d_in[13];
    const float* bo = (const float*)d_in[14];
    const float* Wy = (const float*)d_in[15];
    const float* by = (const float*)d_in[16];

    char* ws = (char*)d_ws;
    unsigned short* Uph = (unsigned short*)(ws + OFF_UHI);
    unsigned short* Upl = (unsigned short*)(ws + OFF_ULO);
    unsigned short* Wxh = (unsigned short*)(ws + OFF_WXHI);
    unsigned short* Wxl = (unsigned short*)(ws + OFF_WXLO);
    unsigned short* Wyh = (unsigned short*)(ws + OFF_WYHI);
    unsigned short* Wyl = (unsigned short*)(ws + OFF_WYLO);
    unsigned* hbuf32    = (unsigned*)(ws + OFF_HBUF);
    unsigned* flags     = (unsigned*)(ws + OFF_FLAGS);
    float* out          = (float*)d_out;

    int prep_total = NPACK_U + NPACK_WX + NPACK_WY + 64;
    int prep_blocks = (prep_total + 255) / 256;
    hipLaunchKernelGGL(lstm_prep, dim3(prep_blocks), dim3(256), 0, stream,
                       Uj, Ui, Uf, Uo, Wj, Wi, Wf, Wo, Wy,
                       Uph, Upl, Wxh, Wxl, Wyh, Wyl, flags);
    hipLaunchKernelGGL(lstm_scan, dim3(64), dim3(256), 0, stream,
                       x, h0, c0, bj, bi, bf, bo, by,
                       Uph, Upl, Wxh, Wxl, Wyh, Wyl, hbuf32, flags, out);
}